// Round 7
// baseline (856.762 us; speedup 1.0000x reference)
//
#include <hip/hip_runtime.h>
#include <cfloat>

#define BB 64
#define NPERB 2048
#define KNN 16
#define NTOT (BB*NPERB)
#define NCAND 24

typedef __bf16 bf16x8 __attribute__((ext_vector_type(8)));
typedef float  f32x4  __attribute__((ext_vector_type(4)));

__device__ __forceinline__ unsigned int med3u(unsigned int a, unsigned int b, unsigned int c) {
    unsigned int d;
    asm("v_med3_u32 %0, %1, %2, %3" : "=v"(d) : "v"(a), "v"(b), "v"(c));
    return d;
}

__device__ __forceinline__ unsigned short bf16rn(float f) {
    unsigned int u = __float_as_uint(f);
    u += 0x7fffu + ((u >> 16) & 1u);
    return (unsigned short)(u >> 16);
}
__device__ __forceinline__ unsigned int pk2(float a, float b) {
    return ((unsigned int)bf16rn(b) << 16) | (unsigned int)bf16rn(a);
}

// Kernel 1 (register-pure rewrite): one row per thread, x in VGPRs, weights via
// wave-uniform (scalar) loads. No LDS, no barriers.
// Bit-exact outputs vs previous version for the selection-critical arrays:
//   - sqnp: numpy pairwise order (identical op sequence to old np_sq64)
//   - xbu : identical bf16 rounding / byte layout
//   - Aout: identical fmaf chain (ascending f, single accumulator, w1m = w1 - w2)
//   - Bvv : identical fmaf chain
__global__ __launch_bounds__(256) void k_transform(const float4* __restrict__ x4,
    const float* __restrict__ w, const float* __restrict__ bias,
    float* __restrict__ Aout, float* __restrict__ Bvv, float* __restrict__ sqnp,
    uint4* __restrict__ xbu4)
{
    const int r = blockIdx.x * 256 + threadIdx.x;
    float xr[64];
#pragma unroll
    for (int j = 0; j < 16; ++j) {
        float4 v = x4[(size_t)r * 16 + j];
        xr[4*j+0] = v.x; xr[4*j+1] = v.y; xr[4*j+2] = v.z; xr[4*j+3] = v.w;
    }

    // numpy pairwise-order sum of squares (same op order as old np_sq64)
    {
        float rr[8];
#pragma unroll
        for (int j = 0; j < 8; ++j) rr[j] = __fmul_rn(xr[j], xr[j]);
#pragma unroll
        for (int i = 1; i < 8; ++i)
#pragma unroll
            for (int j = 0; j < 8; ++j)
                rr[j] = __fadd_rn(rr[j], __fmul_rn(xr[8*i + j], xr[8*i + j]));
        float t01 = __fadd_rn(rr[0], rr[1]);
        float t23 = __fadd_rn(rr[2], rr[3]);
        float t45 = __fadd_rn(rr[4], rr[5]);
        float t67 = __fadd_rn(rr[6], rr[7]);
        sqnp[r] = __fadd_rn(__fadd_rn(t01, t23), __fadd_rn(t45, t67));
    }

    // bf16 copy (identical bytes to previous kernel's pk2 stream)
#pragma unroll
    for (int i = 0; i < 8; ++i) {
        uint4 u;
        u.x = pk2(xr[8*i+0], xr[8*i+1]);
        u.y = pk2(xr[8*i+2], xr[8*i+3]);
        u.z = pk2(xr[8*i+4], xr[8*i+5]);
        u.w = pk2(xr[8*i+6], xr[8*i+7]);
        xbu4[(size_t)r * 8 + i] = u;
    }

    // GEMM: A = x·(W1-W2)^T + b, Bv = x·W2^T.  w row o: [W1 (64) | W2 (64)].
    // Indices into w/bias are wave-uniform -> scalar loads; 8 fmaf chains in flight.
    for (int o = 0; o < 64; o += 4) {
        float a4[4], b4[4];
#pragma unroll
        for (int oo = 0; oo < 4; ++oo) {
            const float* wr = w + (size_t)(o + oo) * 128;
            float a1 = 0.f, a2 = 0.f;
#pragma unroll
            for (int f = 0; f < 64; ++f) {
                float xv  = xr[f];
                float w2v = wr[64 + f];
                float w1m = __fsub_rn(wr[f], w2v);
                a1 = __builtin_fmaf(xv, w1m, a1);
                a2 = __builtin_fmaf(xv, w2v, a2);
            }
            a4[oo] = __fadd_rn(a1, bias[o + oo]);
            b4[oo] = a2;
        }
        *(float4*)&Aout[(size_t)r * 64 + o] = make_float4(a4[0], a4[1], a4[2], a4[3]);
        *(float4*)&Bvv [(size_t)r * 64 + o] = make_float4(b4[0], b4[1], b4[2], b4[3]);
    }
}

// Kernel 2: pipelined dbuf bf16 MFMA -> med3 flat-16 filter -> merge top-24 -> np-exact rescore -> top-16
// LDS shrunk 28160 -> 20480 (rsh aliased onto bsh0; one extra barrier for WAR safety)
// => exactly 8 blocks/CU (160 KiB / 20480), 32 waves/CU; VGPR<=64 pinned via launch_bounds.
__global__ __launch_bounds__(256, 8) void k_topk(const float4* __restrict__ x4,
    const uint4* __restrict__ xb, const float* __restrict__ sq, int* __restrict__ nbr)
{
    // phase1: bsh0 0..9216 | bsh1 9216..18432 | sqc 18432..18944   (rsh aliases bsh0, dead after rf extract)
    // phase2: cand 0..17408 | cand24 17408..20480                  (sqc dead before cand24 written)
    __shared__ __align__(16) char smem[20480];
    unsigned short* bsh0 = (unsigned short*)smem;
    unsigned short* bsh1 = (unsigned short*)(smem + 9216);
    unsigned short* rsh  = (unsigned short*)smem;      // aliased with bsh0
    float* sqc           = (float*)(smem + 18432);     // [2][64]
    unsigned int* cand   = (unsigned int*)smem;        // 64 rows x 68
    unsigned short* cand24 = (unsigned short*)(smem + 17408);

    int t = threadIdx.x;
    int lane = t & 63;
    int w = t >> 6;
    int ln = lane & 15, qd = lane >> 4;
    int batch = blockIdx.x >> 5;
    int strip = blockIdx.x & 31;
    int rbase = batch * NPERB;
    int r0g = rbase + strip * 64;

    // stage block's rows (bf16) + prefetch tile0
    {
        const uint4* src = xb + (size_t)r0g * 8;
#pragma unroll
        for (int i = 0; i < 2; ++i) {
            int l = t + i*256;
            uint4 v = src[l];
            *(uint4*)&rsh[(l >> 3)*72 + (l & 7)*8] = v;
        }
    }
    uint4 pf0, pf1; float sqpf;
    {
        const uint4* src = xb + (size_t)rbase * 8;
        pf0 = src[t]; pf1 = src[t + 256];
        sqpf = (t < 64) ? sq[rbase + t] : 0.f;
    }
    __syncthreads();
    bf16x8 rf0 = *(const bf16x8*)&rsh[(w*16 + ln)*72 + qd*8];
    bf16x8 rf1 = *(const bf16x8*)&rsh[(w*16 + ln)*72 + 32 + qd*8];
    float sqr16 = sq[r0g + w*16 + ln] + 16.f;
    __syncthreads();   // rf extraction complete before bsh0 (== rsh) is overwritten

    // write tile0 -> bsh0, prefetch tile1
    *(uint4*)&bsh0[(t >> 3)*72 + (t & 7)*8] = pf0;
    { int l1 = t + 256; *(uint4*)&bsh0[(l1 >> 3)*72 + (l1 & 7)*8] = pf1; }
    if (t < 64) sqc[t] = sqpf;
    {
        const uint4* src = xb + ((size_t)rbase + 64) * 8;
        pf0 = src[t]; pf1 = src[t + 256];
        sqpf = (t < 64) ? sq[rbase + 64 + t] : 0.f;
    }
    __syncthreads();

    unsigned int ks[16];
#pragma unroll
    for (int j = 0; j < 16; ++j) ks[j] = 0xFFFFFFFFu;

    for (int ct = 0; ct < 32; ++ct) {
        unsigned short* bcur = (ct & 1) ? bsh1 : bsh0;
        const float* sqcur = sqc + (ct & 1)*64;
#pragma unroll
        for (int ct2 = 0; ct2 < 4; ++ct2) {
            int pt = ct2*16 + ln;
            bf16x8 a0 = *(const bf16x8*)&bcur[pt*72 + qd*8];
            bf16x8 a1 = *(const bf16x8*)&bcur[pt*72 + 32 + qd*8];
            f32x4 acc = {0.f, 0.f, 0.f, 0.f};
            acc = __builtin_amdgcn_mfma_f32_16x16x32_bf16(a0, rf0, acc, 0, 0, 0);
            acc = __builtin_amdgcn_mfma_f32_16x16x32_bf16(a1, rf1, acc, 0, 0, 0);
            f32x4 sc4 = *(const f32x4*)&sqcur[ct2*16 + qd*4];
            int idxb = ct*64 + ct2*16 + qd*4;
#pragma unroll
            for (int j = 0; j < 4; ++j) {
                float s = fmaf(-2.f, acc[j], sc4[j] + sqr16);   // > 0 always
                unsigned int u = (__float_as_uint(s) & 0xFFFFF800u) | (unsigned int)(idxb + j);
#pragma unroll
                for (int jj = 15; jj >= 1; --jj) ks[jj] = med3u(u, ks[jj-1], ks[jj]);
                ks[0] = min(ks[0], u);
            }
        }
        if (ct < 31) {
            unsigned short* bnext = (ct & 1) ? bsh0 : bsh1;   // holds tile ct-1: compute done
            *(uint4*)&bnext[(t >> 3)*72 + (t & 7)*8] = pf0;
            { int l1 = t + 256; *(uint4*)&bnext[(l1 >> 3)*72 + (l1 & 7)*8] = pf1; }
            if (t < 64) sqc[((ct + 1) & 1)*64 + t] = sqpf;
            if (ct < 30) {
                const uint4* src = xb + ((size_t)rbase + (ct + 2)*64) * 8;
                pf0 = src[t]; pf1 = src[t + 256];
                sqpf = (t < 64) ? sq[rbase + (ct + 2)*64 + t] : 0.f;
            }
        }
        __syncthreads();
    }

    // dump per-lane keys
    {
        int r = w*16 + ln;
#pragma unroll
        for (int j = 0; j < 16; ++j) cand[r*68 + qd*16 + j] = ks[j];
    }
    __syncthreads();

    // merge to bf16-top-24 per row
    if (t < 64) {
        unsigned int m24[NCAND];
#pragma unroll
        for (int j = 0; j < NCAND; ++j) m24[j] = 0xFFFFFFFFu;
        for (int i = 0; i < 64; ++i) {
            unsigned int u = cand[t*68 + i];
#pragma unroll
            for (int jj = NCAND-1; jj >= 1; --jj) m24[jj] = med3u(u, m24[jj-1], m24[jj]);
            m24[0] = min(m24[0], u);
        }
#pragma unroll
        for (int j = 0; j < NCAND; ++j) cand24[t*NCAND + j] = (unsigned short)(m24[j] & 0x7FFu);
    }
    __syncthreads();

    // np-exact rescore (R6-verified chain): 4 groups x 6 candidates per row
    {
        int r = t & 63, grp = t >> 6;
        float sqr = sq[r0g + r];
        float4 xrA[8];
#pragma unroll
        for (int i = 0; i < 8; ++i) xrA[i] = x4[(size_t)(r0g + r)*16 + i];
        float* kdf = (float*)cand;
#pragma unroll
        for (int m6 = 0; m6 < 6; ++m6) {
            int m = grp*6 + m6;
            int c = (int)cand24[r*NCAND + m];
            const float4* xb4 = &x4[(size_t)(rbase + c)*16];
            float dot = 0.f;
#pragma unroll
            for (int i = 0; i < 8; ++i) {
                float4 a = xrA[i]; float4 b = xb4[i];
                dot = fmaf(a.x, b.x, dot); dot = fmaf(a.y, b.y, dot);
                dot = fmaf(a.z, b.z, dot); dot = fmaf(a.w, b.w, dot);
            }
#pragma unroll
            for (int i = 8; i < 16; ++i) {
                float4 a = x4[(size_t)(r0g + r)*16 + i]; float4 b = xb4[i];
                dot = fmaf(a.x, b.x, dot); dot = fmaf(a.y, b.y, dot);
                dot = fmaf(a.z, b.z, dot); dot = fmaf(a.w, b.w, dot);
            }
            float kd = __fsub_rn(__fadd_rn(sqr, sq[rbase + c]), __fmul_rn(2.0f, dot));
            kdf[r*68 + m] = kd;
            cand[r*68 + 32 + m] = (unsigned int)c;
        }
    }
    __syncthreads();

    // exact top-16 with (key, idx) ordering
    if (t < 64) {
        float* kdf = (float*)cand;
        float dk[KNN]; int di[KNN];
#pragma unroll
        for (int j = 0; j < KNN; ++j) { dk[j] = FLT_MAX; di[j] = 0x7fffffff; }
        for (int m = 0; m < NCAND; ++m) {
            float kd = kdf[t*68 + m];
            int c = (int)cand[t*68 + 32 + m];
            bool better = (kd < dk[KNN-1]) || (kd == dk[KNN-1] && c < di[KNN-1]);
            if (better) {
#pragma unroll
                for (int j = KNN-1; j >= 1; --j) {
                    bool sh = (dk[j-1] > kd) || (dk[j-1] == kd && di[j-1] > c);
                    bool pl = (!sh) && ((dk[j] > kd) || (dk[j] == kd && di[j] > c));
                    float nk = sh ? dk[j-1] : (pl ? kd : dk[j]);
                    int ni = sh ? di[j-1] : (pl ? c : di[j]);
                    dk[j] = nk; di[j] = ni;
                }
                if ((dk[0] > kd) || (dk[0] == kd && di[0] > c)) { dk[0] = kd; di[0] = c; }
            }
        }
#pragma unroll
        for (int k = 0; k < KNN; ++k) nbr[(size_t)(r0g + t)*16 + k] = di[k];
    }
}

// Kernel 3: out[n,o] = relu(out[n,o] + max_k Bv[nbr_k, o])   (out holds A from k1)
__global__ __launch_bounds__(256) void k_combine(const float* __restrict__ Bvv,
    const int* __restrict__ nbr, float* __restrict__ out)
{
    int t = threadIdx.x;
    int row = blockIdx.x*4 + (t >> 6);
    int o = t & 63;
    int rb = (row >> 11) << 11;
    float m = -FLT_MAX;
#pragma unroll
    for (int k = 0; k < 16; ++k) {
        int c = nbr[(size_t)row*16 + k];
        m = fmaxf(m, Bvv[(size_t)(rb + c)*64 + o]);
    }
    out[(size_t)row*64 + o] = fmaxf(out[(size_t)row*64 + o] + m, 0.f);
}

extern "C" void kernel_launch(void* const* d_in, const int* in_sizes, int n_in,
                              void* d_out, int out_size, void* d_ws, size_t ws_size,
                              hipStream_t stream) {
    const float* x    = (const float*)d_in[0];
    // d_in[1] = batch (contiguous per batch; unused)
    const float* w    = (const float*)d_in[2];
    const float* bias = (const float*)d_in[3];
    float* out = (float*)d_out;

    float* Bvv  = (float*)d_ws;                       // 32 MB
    float* sqnp = Bvv + (size_t)NTOT * 64;            // 0.5 MB
    int*   nbr  = (int*)(sqnp + NTOT);                // 8 MB
    unsigned int* xbu = (unsigned int*)(nbr + (size_t)NTOT * 16);   // 16 MB bf16 x

    k_transform<<<NTOT/256, 256, 0, stream>>>((const float4*)x, w, bias, out, Bvv, sqnp, (uint4*)xbu);
    k_topk<<<2048, 256, 0, stream>>>((const float4*)x, (const uint4*)xbu, sqnp, nbr);
    k_combine<<<NTOT/4, 256, 0, stream>>>(Bvv, nbr, out);
}

// Round 8
// 774.721 us; speedup vs baseline: 1.1059x; 1.1059x over previous
//
#include <hip/hip_runtime.h>
#include <cfloat>

#define BB 64
#define NPERB 2048
#define KNN 16
#define NTOT (BB*NPERB)
#define NCAND 24

typedef __bf16 bf16x8 __attribute__((ext_vector_type(8)));
typedef float  f32x4  __attribute__((ext_vector_type(4)));

__device__ __forceinline__ unsigned int med3u(unsigned int a, unsigned int b, unsigned int c) {
    unsigned int d;
    asm("v_med3_u32 %0, %1, %2, %3" : "=v"(d) : "v"(a), "v"(b), "v"(c));
    return d;
}

__device__ __forceinline__ unsigned short bf16rn(float f) {
    unsigned int u = __float_as_uint(f);
    u += 0x7fffu + ((u >> 16) & 1u);
    return (unsigned short)(u >> 16);
}
__device__ __forceinline__ unsigned int pk2(float a, float b) {
    return ((unsigned int)bf16rn(b) << 16) | (unsigned int)bf16rn(a);
}

// Kernel 1: register-pure compute, but x staged through LDS for coalesced
// global loads (R7 fix: direct per-row loads were 256-B-stride uncoalesced,
// thrashing L1 at 2 waves/SIMD).
// LDS stride 68 floats = 272 B: 16-B aligned for float4 ops; read-back bank
// pattern 8-way (one-time ~500 cyc/wave, negligible).
// Compute chains BYTE-IDENTICAL to the R7-passing version:
//   - sqnp: numpy pairwise order
//   - xbu : same pk2 rounding / byte layout
//   - Aout/Bvv: same ascending-f single-accumulator fmaf chains, w1m = w1 - w2
__global__ __launch_bounds__(256) void k_transform(const float4* __restrict__ x4,
    const float* __restrict__ w, const float* __restrict__ bias,
    float* __restrict__ Aout, float* __restrict__ Bvv, float* __restrict__ sqnp,
    uint4* __restrict__ xbu4)
{
    __shared__ __align__(16) float xs[256*68];   // 69,632 B -> 2 blocks/CU
    const int t = threadIdx.x;
    const int r0 = blockIdx.x * 256;
    const int r = r0 + t;

    // coalesced stage: 4096 float4 per block, 16 per thread
#pragma unroll
    for (int i = 0; i < 16; ++i) {
        int l4 = t + i*256;                 // float4 index in tile
        float4 v = x4[(size_t)r0*16 + l4];
        int row = l4 >> 4;                  // 16 float4 per row
        int f0  = (l4 & 15) * 4;
        *(float4*)&xs[row*68 + f0] = v;     // 272-B row stride: 16-B aligned
    }
    __syncthreads();

    float xr[64];
#pragma unroll
    for (int j = 0; j < 16; ++j) {
        float4 v = *(const float4*)&xs[t*68 + j*4];
        xr[4*j+0] = v.x; xr[4*j+1] = v.y; xr[4*j+2] = v.z; xr[4*j+3] = v.w;
    }

    // numpy pairwise-order sum of squares (unchanged op sequence)
    {
        float rr[8];
#pragma unroll
        for (int j = 0; j < 8; ++j) rr[j] = __fmul_rn(xr[j], xr[j]);
#pragma unroll
        for (int i = 1; i < 8; ++i)
#pragma unroll
            for (int j = 0; j < 8; ++j)
                rr[j] = __fadd_rn(rr[j], __fmul_rn(xr[8*i + j], xr[8*i + j]));
        float t01 = __fadd_rn(rr[0], rr[1]);
        float t23 = __fadd_rn(rr[2], rr[3]);
        float t45 = __fadd_rn(rr[4], rr[5]);
        float t67 = __fadd_rn(rr[6], rr[7]);
        sqnp[r] = __fadd_rn(__fadd_rn(t01, t23), __fadd_rn(t45, t67));
    }

    // bf16 copy (identical bytes)
#pragma unroll
    for (int i = 0; i < 8; ++i) {
        uint4 u;
        u.x = pk2(xr[8*i+0], xr[8*i+1]);
        u.y = pk2(xr[8*i+2], xr[8*i+3]);
        u.z = pk2(xr[8*i+4], xr[8*i+5]);
        u.w = pk2(xr[8*i+6], xr[8*i+7]);
        xbu4[(size_t)r * 8 + i] = u;
    }

    // GEMM: A = x·(W1-W2)^T + b, Bv = x·W2^T.  w row o: [W1 (64) | W2 (64)].
    // w/bias indices are wave-uniform -> scalar loads; 8 fmaf chains in flight.
    for (int o = 0; o < 64; o += 4) {
        float a4[4], b4[4];
#pragma unroll
        for (int oo = 0; oo < 4; ++oo) {
            const float* wr = w + (size_t)(o + oo) * 128;
            float a1 = 0.f, a2 = 0.f;
#pragma unroll
            for (int f = 0; f < 64; ++f) {
                float xv  = xr[f];
                float w2v = wr[64 + f];
                float w1m = __fsub_rn(wr[f], w2v);
                a1 = __builtin_fmaf(xv, w1m, a1);
                a2 = __builtin_fmaf(xv, w2v, a2);
            }
            a4[oo] = __fadd_rn(a1, bias[o + oo]);
            b4[oo] = a2;
        }
        *(float4*)&Aout[(size_t)r * 64 + o] = make_float4(a4[0], a4[1], a4[2], a4[3]);
        *(float4*)&Bvv [(size_t)r * 64 + o] = make_float4(b4[0], b4[1], b4[2], b4[3]);
    }
}

// Kernel 2: pipelined dbuf bf16 MFMA -> med3 flat-16 filter -> merge top-24 -> np-exact rescore -> top-16
// LDS 20480 kept (rsh aliased onto bsh0 + WAR barrier).
// R7 fix: launch_bounds back to (256,4) — the (256,8) cap cut VGPR 64->32 and
// caused scratch spills (WRITE_SIZE 24->172 MB, FETCH +293 MB). At natural
// 64 VGPR, 8 waves/SIMD are still possible and LDS allows exactly 8 blocks/CU.
__global__ __launch_bounds__(256, 4) void k_topk(const float4* __restrict__ x4,
    const uint4* __restrict__ xb, const float* __restrict__ sq, int* __restrict__ nbr)
{
    // phase1: bsh0 0..9216 | bsh1 9216..18432 | sqc 18432..18944   (rsh aliases bsh0, dead after rf extract)
    // phase2: cand 0..17408 | cand24 17408..20480                  (sqc dead before cand24 written)
    __shared__ __align__(16) char smem[20480];
    unsigned short* bsh0 = (unsigned short*)smem;
    unsigned short* bsh1 = (unsigned short*)(smem + 9216);
    unsigned short* rsh  = (unsigned short*)smem;      // aliased with bsh0
    float* sqc           = (float*)(smem + 18432);     // [2][64]
    unsigned int* cand   = (unsigned int*)smem;        // 64 rows x 68
    unsigned short* cand24 = (unsigned short*)(smem + 17408);

    int t = threadIdx.x;
    int lane = t & 63;
    int w = t >> 6;
    int ln = lane & 15, qd = lane >> 4;
    int batch = blockIdx.x >> 5;
    int strip = blockIdx.x & 31;
    int rbase = batch * NPERB;
    int r0g = rbase + strip * 64;

    // stage block's rows (bf16) + prefetch tile0
    {
        const uint4* src = xb + (size_t)r0g * 8;
#pragma unroll
        for (int i = 0; i < 2; ++i) {
            int l = t + i*256;
            uint4 v = src[l];
            *(uint4*)&rsh[(l >> 3)*72 + (l & 7)*8] = v;
        }
    }
    uint4 pf0, pf1; float sqpf;
    {
        const uint4* src = xb + (size_t)rbase * 8;
        pf0 = src[t]; pf1 = src[t + 256];
        sqpf = (t < 64) ? sq[rbase + t] : 0.f;
    }
    __syncthreads();
    bf16x8 rf0 = *(const bf16x8*)&rsh[(w*16 + ln)*72 + qd*8];
    bf16x8 rf1 = *(const bf16x8*)&rsh[(w*16 + ln)*72 + 32 + qd*8];
    float sqr16 = sq[r0g + w*16 + ln] + 16.f;
    __syncthreads();   // rf extraction complete before bsh0 (== rsh) is overwritten

    // write tile0 -> bsh0, prefetch tile1
    *(uint4*)&bsh0[(t >> 3)*72 + (t & 7)*8] = pf0;
    { int l1 = t + 256; *(uint4*)&bsh0[(l1 >> 3)*72 + (l1 & 7)*8] = pf1; }
    if (t < 64) sqc[t] = sqpf;
    {
        const uint4* src = xb + ((size_t)rbase + 64) * 8;
        pf0 = src[t]; pf1 = src[t + 256];
        sqpf = (t < 64) ? sq[rbase + 64 + t] : 0.f;
    }
    __syncthreads();

    unsigned int ks[16];
#pragma unroll
    for (int j = 0; j < 16; ++j) ks[j] = 0xFFFFFFFFu;

    for (int ct = 0; ct < 32; ++ct) {
        unsigned short* bcur = (ct & 1) ? bsh1 : bsh0;
        const float* sqcur = sqc + (ct & 1)*64;
#pragma unroll
        for (int ct2 = 0; ct2 < 4; ++ct2) {
            int pt = ct2*16 + ln;
            bf16x8 a0 = *(const bf16x8*)&bcur[pt*72 + qd*8];
            bf16x8 a1 = *(const bf16x8*)&bcur[pt*72 + 32 + qd*8];
            f32x4 acc = {0.f, 0.f, 0.f, 0.f};
            acc = __builtin_amdgcn_mfma_f32_16x16x32_bf16(a0, rf0, acc, 0, 0, 0);
            acc = __builtin_amdgcn_mfma_f32_16x16x32_bf16(a1, rf1, acc, 0, 0, 0);
            f32x4 sc4 = *(const f32x4*)&sqcur[ct2*16 + qd*4];
            int idxb = ct*64 + ct2*16 + qd*4;
#pragma unroll
            for (int j = 0; j < 4; ++j) {
                float s = fmaf(-2.f, acc[j], sc4[j] + sqr16);   // > 0 always
                unsigned int u = (__float_as_uint(s) & 0xFFFFF800u) | (unsigned int)(idxb + j);
#pragma unroll
                for (int jj = 15; jj >= 1; --jj) ks[jj] = med3u(u, ks[jj-1], ks[jj]);
                ks[0] = min(ks[0], u);
            }
        }
        if (ct < 31) {
            unsigned short* bnext = (ct & 1) ? bsh0 : bsh1;   // holds tile ct-1: compute done
            *(uint4*)&bnext[(t >> 3)*72 + (t & 7)*8] = pf0;
            { int l1 = t + 256; *(uint4*)&bnext[(l1 >> 3)*72 + (l1 & 7)*8] = pf1; }
            if (t < 64) sqc[((ct + 1) & 1)*64 + t] = sqpf;
            if (ct < 30) {
                const uint4* src = xb + ((size_t)rbase + (ct + 2)*64) * 8;
                pf0 = src[t]; pf1 = src[t + 256];
                sqpf = (t < 64) ? sq[rbase + (ct + 2)*64 + t] : 0.f;
            }
        }
        __syncthreads();
    }

    // dump per-lane keys
    {
        int r = w*16 + ln;
#pragma unroll
        for (int j = 0; j < 16; ++j) cand[r*68 + qd*16 + j] = ks[j];
    }
    __syncthreads();

    // merge to bf16-top-24 per row
    if (t < 64) {
        unsigned int m24[NCAND];
#pragma unroll
        for (int j = 0; j < NCAND; ++j) m24[j] = 0xFFFFFFFFu;
        for (int i = 0; i < 64; ++i) {
            unsigned int u = cand[t*68 + i];
#pragma unroll
            for (int jj = NCAND-1; jj >= 1; --jj) m24[jj] = med3u(u, m24[jj-1], m24[jj]);
            m24[0] = min(m24[0], u);
        }
#pragma unroll
        for (int j = 0; j < NCAND; ++j) cand24[t*NCAND + j] = (unsigned short)(m24[j] & 0x7FFu);
    }
    __syncthreads();

    // np-exact rescore (R6-verified chain): 4 groups x 6 candidates per row
    {
        int r = t & 63, grp = t >> 6;
        float sqr = sq[r0g + r];
        float4 xrA[8];
#pragma unroll
        for (int i = 0; i < 8; ++i) xrA[i] = x4[(size_t)(r0g + r)*16 + i];
        float* kdf = (float*)cand;
#pragma unroll
        for (int m6 = 0; m6 < 6; ++m6) {
            int m = grp*6 + m6;
            int c = (int)cand24[r*NCAND + m];
            const float4* xb4 = &x4[(size_t)(rbase + c)*16];
            float dot = 0.f;
#pragma unroll
            for (int i = 0; i < 8; ++i) {
                float4 a = xrA[i]; float4 b = xb4[i];
                dot = fmaf(a.x, b.x, dot); dot = fmaf(a.y, b.y, dot);
                dot = fmaf(a.z, b.z, dot); dot = fmaf(a.w, b.w, dot);
            }
#pragma unroll
            for (int i = 8; i < 16; ++i) {
                float4 a = x4[(size_t)(r0g + r)*16 + i]; float4 b = xb4[i];
                dot = fmaf(a.x, b.x, dot); dot = fmaf(a.y, b.y, dot);
                dot = fmaf(a.z, b.z, dot); dot = fmaf(a.w, b.w, dot);
            }
            float kd = __fsub_rn(__fadd_rn(sqr, sq[rbase + c]), __fmul_rn(2.0f, dot));
            kdf[r*68 + m] = kd;
            cand[r*68 + 32 + m] = (unsigned int)c;
        }
    }
    __syncthreads();

    // exact top-16 with (key, idx) ordering
    if (t < 64) {
        float* kdf = (float*)cand;
        float dk[KNN]; int di[KNN];
#pragma unroll
        for (int j = 0; j < KNN; ++j) { dk[j] = FLT_MAX; di[j] = 0x7fffffff; }
        for (int m = 0; m < NCAND; ++m) {
            float kd = kdf[t*68 + m];
            int c = (int)cand[t*68 + 32 + m];
            bool better = (kd < dk[KNN-1]) || (kd == dk[KNN-1] && c < di[KNN-1]);
            if (better) {
#pragma unroll
                for (int j = KNN-1; j >= 1; --j) {
                    bool sh = (dk[j-1] > kd) || (dk[j-1] == kd && di[j-1] > c);
                    bool pl = (!sh) && ((dk[j] > kd) || (dk[j] == kd && di[j] > c));
                    float nk = sh ? dk[j-1] : (pl ? kd : dk[j]);
                    int ni = sh ? di[j-1] : (pl ? c : di[j]);
                    dk[j] = nk; di[j] = ni;
                }
                if ((dk[0] > kd) || (dk[0] == kd && di[0] > c)) { dk[0] = kd; di[0] = c; }
            }
        }
#pragma unroll
        for (int k = 0; k < KNN; ++k) nbr[(size_t)(r0g + t)*16 + k] = di[k];
    }
}

// Kernel 3: out[n,o] = relu(out[n,o] + max_k Bv[nbr_k, o])   (out holds A from k1)
__global__ __launch_bounds__(256) void k_combine(const float* __restrict__ Bvv,
    const int* __restrict__ nbr, float* __restrict__ out)
{
    int t = threadIdx.x;
    int row = blockIdx.x*4 + (t >> 6);
    int o = t & 63;
    int rb = (row >> 11) << 11;
    float m = -FLT_MAX;
#pragma unroll
    for (int k = 0; k < 16; ++k) {
        int c = nbr[(size_t)row*16 + k];
        m = fmaxf(m, Bvv[(size_t)(rb + c)*64 + o]);
    }
    out[(size_t)row*64 + o] = fmaxf(out[(size_t)row*64 + o] + m, 0.f);
}

extern "C" void kernel_launch(void* const* d_in, const int* in_sizes, int n_in,
                              void* d_out, int out_size, void* d_ws, size_t ws_size,
                              hipStream_t stream) {
    const float* x    = (const float*)d_in[0];
    // d_in[1] = batch (contiguous per batch; unused)
    const float* w    = (const float*)d_in[2];
    const float* bias = (const float*)d_in[3];
    float* out = (float*)d_out;

    float* Bvv  = (float*)d_ws;                       // 32 MB
    float* sqnp = Bvv + (size_t)NTOT * 64;            // 0.5 MB
    int*   nbr  = (int*)(sqnp + NTOT);                // 8 MB
    unsigned int* xbu = (unsigned int*)(nbr + (size_t)NTOT * 16);   // 16 MB bf16 x

    k_transform<<<NTOT/256, 256, 0, stream>>>((const float4*)x, w, bias, out, Bvv, sqnp, (uint4*)xbu);
    k_topk<<<2048, 256, 0, stream>>>((const float4*)x, (const uint4*)xbu, sqnp, nbr);
    k_combine<<<NTOT/4, 256, 0, stream>>>(Bvv, nbr, out);
}

// Round 10
// 588.040 us; speedup vs baseline: 1.4570x; 1.3175x over previous
//
#include <hip/hip_runtime.h>
#include <cfloat>

#define BB 64
#define NPERB 2048
#define KNN 16
#define NTOT (BB*NPERB)
#define NCAND 24

typedef __bf16 bf16x8 __attribute__((ext_vector_type(8)));
typedef float  f32x4  __attribute__((ext_vector_type(4)));

__device__ __forceinline__ unsigned int med3u(unsigned int a, unsigned int b, unsigned int c) {
    unsigned int d;
    asm("v_med3_u32 %0, %1, %2, %3" : "=v"(d) : "v"(a), "v"(b), "v"(c));
    return d;
}

__device__ __forceinline__ unsigned short bf16rn(float f) {
    unsigned int u = __float_as_uint(f);
    u += 0x7fffu + ((u >> 16) & 1u);
    return (unsigned short)(u >> 16);
}
__device__ __forceinline__ unsigned int pk2(float a, float b) {
    return ((unsigned int)bf16rn(b) << 16) | (unsigned int)bf16rn(a);
}

// Kernel 1 (R8 post-mortem fix): one row per thread, x in VGPRs via direct
// float4 loads (256 unique lines/wave, fully used -> fine), and W staged in
// LDS in [o][f] layout read as wave-uniform b128 BROADCASTS (zero conflicts).
// R7/R8's ~300us came from per-(o,f) global w loads thrashing the 32KB L1.
// All chains value-identical to the R0-passing version:
//   - sqnp: numpy pairwise tree
//   - xbu : same pk2 rounding/byte layout
//   - a1  : ascending-f single-accumulator fma of x*(w1-w2), w1m pre-subtracted
//   - a2  : ascending-f single-accumulator fma of x*w2
__global__ __launch_bounds__(256) void k_transform(const float4* __restrict__ x4,
    const float* __restrict__ w, const float* __restrict__ bias,
    float* __restrict__ Aout, float* __restrict__ Bvv, float* __restrict__ sqnp,
    uint4* __restrict__ xbu4)
{
    __shared__ __align__(16) float wm[64*64];    // (w1-w2)[o][f]
    __shared__ __align__(16) float w2m[64*64];   // w2[o][f]
    const int t = threadIdx.x;
    const int r = blockIdx.x * 256 + t;

    // stage weights: 4096 (o,f) pairs, coalesced within each 64-lane segment
#pragma unroll
    for (int i = 0; i < 16; ++i) {
        int e = t + i*256;
        int o = e >> 6, f = e & 63;
        float w1 = w[o*128 + f];
        float w2 = w[o*128 + 64 + f];
        wm[e]  = w1 - w2;
        w2m[e] = w2;
    }

    float xr[64];
#pragma unroll
    for (int j = 0; j < 16; ++j) {
        float4 v = x4[(size_t)r * 16 + j];
        xr[4*j+0] = v.x; xr[4*j+1] = v.y; xr[4*j+2] = v.z; xr[4*j+3] = v.w;
    }

    // numpy pairwise-order sum of squares (unchanged op tree)
    {
        float rr[8];
#pragma unroll
        for (int j = 0; j < 8; ++j) rr[j] = __fmul_rn(xr[j], xr[j]);
#pragma unroll
        for (int i = 1; i < 8; ++i)
#pragma unroll
            for (int j = 0; j < 8; ++j)
                rr[j] = __fadd_rn(rr[j], __fmul_rn(xr[8*i + j], xr[8*i + j]));
        float t01 = __fadd_rn(rr[0], rr[1]);
        float t23 = __fadd_rn(rr[2], rr[3]);
        float t45 = __fadd_rn(rr[4], rr[5]);
        float t67 = __fadd_rn(rr[6], rr[7]);
        sqnp[r] = __fadd_rn(__fadd_rn(t01, t23), __fadd_rn(t45, t67));
    }

    // bf16 copy (identical bytes)
#pragma unroll
    for (int i = 0; i < 8; ++i) {
        uint4 u;
        u.x = pk2(xr[8*i+0], xr[8*i+1]);
        u.y = pk2(xr[8*i+2], xr[8*i+3]);
        u.z = pk2(xr[8*i+4], xr[8*i+5]);
        u.w = pk2(xr[8*i+6], xr[8*i+7]);
        xbu4[(size_t)r * 8 + i] = u;
    }

    __syncthreads();   // weights staged

    // GEMM from LDS broadcasts: per o, 32 uniform ds_read_b128 + 128 fma
    for (int o = 0; o < 64; o += 4) {
        float a4[4], b4[4];
#pragma unroll
        for (int oo = 0; oo < 4; ++oo) {
            const float* wmr  = &wm [(o + oo)*64];
            const float* w2mr = &w2m[(o + oo)*64];
            float a1 = 0.f, a2 = 0.f;
#pragma unroll
            for (int fi = 0; fi < 16; ++fi) {
                f32x4 wa = *(const f32x4*)&wmr [fi*4];
                f32x4 wb = *(const f32x4*)&w2mr[fi*4];
#pragma unroll
                for (int k = 0; k < 4; ++k) {
                    float xv = xr[fi*4 + k];
                    a1 = __builtin_fmaf(xv, wa[k], a1);
                    a2 = __builtin_fmaf(xv, wb[k], a2);
                }
            }
            a4[oo] = __fadd_rn(a1, bias[o + oo]);
            b4[oo] = a2;
        }
        *(float4*)&Aout[(size_t)r * 64 + o] = make_float4(a4[0], a4[1], a4[2], a4[3]);
        *(float4*)&Bvv [(size_t)r * 64 + o] = make_float4(b4[0], b4[1], b4[2], b4[3]);
    }
}

// Kernel 2: EXACT revert to the R0 baseline (proven fastest: 421 us).
// R7/R8 lessons: (256,8) reg-cap -> spills; LDS 20480 -> occupancy unchanged
// at ~35% but +1 barrier cost. Static-occupancy levers are refuted here.
__global__ __launch_bounds__(256, 4) void k_topk(const float4* __restrict__ x4,
    const uint4* __restrict__ xb, const float* __restrict__ sq, int* __restrict__ nbr)
{
    // phase1: bsh0 0..9216 | bsh1 9216..18432 | rsh 18432..27648 | sqc 27648..28160
    // phase2: cand 0..17408 | cand24 17408..20480
    __shared__ __align__(16) char smem[28160];
    unsigned short* bsh0 = (unsigned short*)smem;
    unsigned short* bsh1 = (unsigned short*)(smem + 9216);
    unsigned short* rsh  = (unsigned short*)(smem + 18432);
    float* sqc           = (float*)(smem + 27648);     // [2][64]
    unsigned int* cand   = (unsigned int*)smem;        // 64 rows x 68
    unsigned short* cand24 = (unsigned short*)(smem + 17408);

    int t = threadIdx.x;
    int lane = t & 63;
    int w = t >> 6;
    int ln = lane & 15, qd = lane >> 4;
    int batch = blockIdx.x >> 5;
    int strip = blockIdx.x & 31;
    int rbase = batch * NPERB;
    int r0g = rbase + strip * 64;

    // stage block's rows (bf16) + prefetch tile0
    {
        const uint4* src = xb + (size_t)r0g * 8;
#pragma unroll
        for (int i = 0; i < 2; ++i) {
            int l = t + i*256;
            uint4 v = src[l];
            *(uint4*)&rsh[(l >> 3)*72 + (l & 7)*8] = v;
        }
    }
    uint4 pf0, pf1; float sqpf;
    {
        const uint4* src = xb + (size_t)rbase * 8;
        pf0 = src[t]; pf1 = src[t + 256];
        sqpf = (t < 64) ? sq[rbase + t] : 0.f;
    }
    __syncthreads();
    bf16x8 rf0 = *(const bf16x8*)&rsh[(w*16 + ln)*72 + qd*8];
    bf16x8 rf1 = *(const bf16x8*)&rsh[(w*16 + ln)*72 + 32 + qd*8];
    float sqr16 = sq[r0g + w*16 + ln] + 16.f;

    // write tile0 -> bsh0, prefetch tile1
    *(uint4*)&bsh0[(t >> 3)*72 + (t & 7)*8] = pf0;
    { int l1 = t + 256; *(uint4*)&bsh0[(l1 >> 3)*72 + (l1 & 7)*8] = pf1; }
    if (t < 64) sqc[t] = sqpf;
    {
        const uint4* src = xb + ((size_t)rbase + 64) * 8;
        pf0 = src[t]; pf1 = src[t + 256];
        sqpf = (t < 64) ? sq[rbase + 64 + t] : 0.f;
    }
    __syncthreads();

    unsigned int ks[16];
#pragma unroll
    for (int j = 0; j < 16; ++j) ks[j] = 0xFFFFFFFFu;

    for (int ct = 0; ct < 32; ++ct) {
        unsigned short* bcur = (ct & 1) ? bsh1 : bsh0;
        const float* sqcur = sqc + (ct & 1)*64;
#pragma unroll
        for (int ct2 = 0; ct2 < 4; ++ct2) {
            int pt = ct2*16 + ln;
            bf16x8 a0 = *(const bf16x8*)&bcur[pt*72 + qd*8];
            bf16x8 a1 = *(const bf16x8*)&bcur[pt*72 + 32 + qd*8];
            f32x4 acc = {0.f, 0.f, 0.f, 0.f};
            acc = __builtin_amdgcn_mfma_f32_16x16x32_bf16(a0, rf0, acc, 0, 0, 0);
            acc = __builtin_amdgcn_mfma_f32_16x16x32_bf16(a1, rf1, acc, 0, 0, 0);
            f32x4 sc4 = *(const f32x4*)&sqcur[ct2*16 + qd*4];
            int idxb = ct*64 + ct2*16 + qd*4;
#pragma unroll
            for (int j = 0; j < 4; ++j) {
                float s = fmaf(-2.f, acc[j], sc4[j] + sqr16);   // > 0 always
                unsigned int u = (__float_as_uint(s) & 0xFFFFF800u) | (unsigned int)(idxb + j);
#pragma unroll
                for (int jj = 15; jj >= 1; --jj) ks[jj] = med3u(u, ks[jj-1], ks[jj]);
                ks[0] = min(ks[0], u);
            }
        }
        if (ct < 31) {
            unsigned short* bnext = (ct & 1) ? bsh0 : bsh1;   // holds tile ct-1: compute done
            *(uint4*)&bnext[(t >> 3)*72 + (t & 7)*8] = pf0;
            { int l1 = t + 256; *(uint4*)&bnext[(l1 >> 3)*72 + (l1 & 7)*8] = pf1; }
            if (t < 64) sqc[((ct + 1) & 1)*64 + t] = sqpf;
            if (ct < 30) {
                const uint4* src = xb + ((size_t)rbase + (ct + 2)*64) * 8;
                pf0 = src[t]; pf1 = src[t + 256];
                sqpf = (t < 64) ? sq[rbase + (ct + 2)*64 + t] : 0.f;
            }
        }
        __syncthreads();
    }

    // dump per-lane keys
    {
        int r = w*16 + ln;
#pragma unroll
        for (int j = 0; j < 16; ++j) cand[r*68 + qd*16 + j] = ks[j];
    }
    __syncthreads();

    // merge to bf16-top-24 per row
    if (t < 64) {
        unsigned int m24[NCAND];
#pragma unroll
        for (int j = 0; j < NCAND; ++j) m24[j] = 0xFFFFFFFFu;
        for (int i = 0; i < 64; ++i) {
            unsigned int u = cand[t*68 + i];
#pragma unroll
            for (int jj = NCAND-1; jj >= 1; --jj) m24[jj] = med3u(u, m24[jj-1], m24[jj]);
            m24[0] = min(m24[0], u);
        }
#pragma unroll
        for (int j = 0; j < NCAND; ++j) cand24[t*NCAND + j] = (unsigned short)(m24[j] & 0x7FFu);
    }
    __syncthreads();

    // np-exact rescore (R6-verified chain): 4 groups x 6 candidates per row
    {
        int r = t & 63, grp = t >> 6;
        float sqr = sq[r0g + r];
        float4 xrA[8];
#pragma unroll
        for (int i = 0; i < 8; ++i) xrA[i] = x4[(size_t)(r0g + r)*16 + i];
        float* kdf = (float*)cand;
#pragma unroll
        for (int m6 = 0; m6 < 6; ++m6) {
            int m = grp*6 + m6;
            int c = (int)cand24[r*NCAND + m];
            const float4* xb4 = &x4[(size_t)(rbase + c)*16];
            float dot = 0.f;
#pragma unroll
            for (int i = 0; i < 8; ++i) {
                float4 a = xrA[i]; float4 b = xb4[i];
                dot = fmaf(a.x, b.x, dot); dot = fmaf(a.y, b.y, dot);
                dot = fmaf(a.z, b.z, dot); dot = fmaf(a.w, b.w, dot);
            }
#pragma unroll
            for (int i = 8; i < 16; ++i) {
                float4 a = x4[(size_t)(r0g + r)*16 + i]; float4 b = xb4[i];
                dot = fmaf(a.x, b.x, dot); dot = fmaf(a.y, b.y, dot);
                dot = fmaf(a.z, b.z, dot); dot = fmaf(a.w, b.w, dot);
            }
            float kd = __fsub_rn(__fadd_rn(sqr, sq[rbase + c]), __fmul_rn(2.0f, dot));
            kdf[r*68 + m] = kd;
            cand[r*68 + 32 + m] = (unsigned int)c;
        }
    }
    __syncthreads();

    // exact top-16 with (key, idx) ordering
    if (t < 64) {
        float* kdf = (float*)cand;
        float dk[KNN]; int di[KNN];
#pragma unroll
        for (int j = 0; j < KNN; ++j) { dk[j] = FLT_MAX; di[j] = 0x7fffffff; }
        for (int m = 0; m < NCAND; ++m) {
            float kd = kdf[t*68 + m];
            int c = (int)cand[t*68 + 32 + m];
            bool better = (kd < dk[KNN-1]) || (kd == dk[KNN-1] && c < di[KNN-1]);
            if (better) {
#pragma unroll
                for (int j = KNN-1; j >= 1; --j) {
                    bool sh = (dk[j-1] > kd) || (dk[j-1] == kd && di[j-1] > c);
                    bool pl = (!sh) && ((dk[j] > kd) || (dk[j] == kd && di[j] > c));
                    float nk = sh ? dk[j-1] : (pl ? kd : dk[j]);
                    int ni = sh ? di[j-1] : (pl ? c : di[j]);
                    dk[j] = nk; di[j] = ni;
                }
                if ((dk[0] > kd) || (dk[0] == kd && di[0] > c)) { dk[0] = kd; di[0] = c; }
            }
        }
#pragma unroll
        for (int k = 0; k < KNN; ++k) nbr[(size_t)(r0g + t)*16 + k] = di[k];
    }
}

// Kernel 3: out[n,o] = relu(out[n,o] + max_k Bv[nbr_k, o])   (out holds A from k1)
__global__ __launch_bounds__(256) void k_combine(const float* __restrict__ Bvv,
    const int* __restrict__ nbr, float* __restrict__ out)
{
    int t = threadIdx.x;
    int row = blockIdx.x*4 + (t >> 6);
    int o = t & 63;
    int rb = (row >> 11) << 11;
    float m = -FLT_MAX;
#pragma unroll
    for (int k = 0; k < 16; ++k) {
        int c = nbr[(size_t)row*16 + k];
        m = fmaxf(m, Bvv[(size_t)(rb + c)*64 + o]);
    }
    out[(size_t)row*64 + o] = fmaxf(out[(size_t)row*64 + o] + m, 0.f);
}

extern "C" void kernel_launch(void* const* d_in, const int* in_sizes, int n_in,
                              void* d_out, int out_size, void* d_ws, size_t ws_size,
                              hipStream_t stream) {
    const float* x    = (const float*)d_in[0];
    // d_in[1] = batch (contiguous per batch; unused)
    const float* w    = (const float*)d_in[2];
    const float* bias = (const float*)d_in[3];
    float* out = (float*)d_out;

    float* Bvv  = (float*)d_ws;                       // 32 MB
    float* sqnp = Bvv + (size_t)NTOT * 64;            // 0.5 MB
    int*   nbr  = (int*)(sqnp + NTOT);                // 8 MB
    unsigned int* xbu = (unsigned int*)(nbr + (size_t)NTOT * 16);   // 16 MB bf16 x

    k_transform<<<NTOT/256, 256, 0, stream>>>((const float4*)x, w, bias, out, Bvv, sqnp, (uint4*)xbu);
    k_topk<<<2048, 256, 0, stream>>>((const float4*)x, (const uint4*)xbu, sqnp, nbr);
    k_combine<<<NTOT/4, 256, 0, stream>>>(Bvv, nbr, out);
}

// Round 12
// 530.878 us; speedup vs baseline: 1.6139x; 1.1077x over previous
//
#include <hip/hip_runtime.h>
#include <cfloat>

#define BB 64
#define NPERB 2048
#define KNN 16
#define NTOT (BB*NPERB)
#define NCAND 24

typedef __bf16 bf16x8 __attribute__((ext_vector_type(8)));
typedef float  f32x4  __attribute__((ext_vector_type(4)));

__device__ __forceinline__ unsigned int med3u(unsigned int a, unsigned int b, unsigned int c) {
    unsigned int d;
    asm("v_med3_u32 %0, %1, %2, %3" : "=v"(d) : "v"(a), "v"(b), "v"(c));
    return d;
}

__device__ __forceinline__ unsigned short bf16rn(float f) {
    unsigned int u = __float_as_uint(f);
    u += 0x7fffu + ((u >> 16) & 1u);
    return (unsigned short)(u >> 16);
}
__device__ __forceinline__ unsigned int pk2(float a, float b) {
    return ((unsigned int)bf16rn(b) << 16) | (unsigned int)bf16rn(a);
}

// Kernel 1: unchanged from R9/R10 (W staged in LDS [o][f], wave-uniform b128
// broadcasts; chains value-identical to R0).
__global__ __launch_bounds__(256) void k_transform(const float4* __restrict__ x4,
    const float* __restrict__ w, const float* __restrict__ bias,
    float* __restrict__ Aout, float* __restrict__ Bvv, float* __restrict__ sqnp,
    uint4* __restrict__ xbu4)
{
    __shared__ __align__(16) float wm[64*64];    // (w1-w2)[o][f]
    __shared__ __align__(16) float w2m[64*64];   // w2[o][f]
    const int t = threadIdx.x;
    const int r = blockIdx.x * 256 + t;

#pragma unroll
    for (int i = 0; i < 16; ++i) {
        int e = t + i*256;
        int o = e >> 6, f = e & 63;
        float w1 = w[o*128 + f];
        float w2 = w[o*128 + 64 + f];
        wm[e]  = w1 - w2;
        w2m[e] = w2;
    }

    float xr[64];
#pragma unroll
    for (int j = 0; j < 16; ++j) {
        float4 v = x4[(size_t)r * 16 + j];
        xr[4*j+0] = v.x; xr[4*j+1] = v.y; xr[4*j+2] = v.z; xr[4*j+3] = v.w;
    }

    // numpy pairwise-order sum of squares (unchanged op tree)
    {
        float rr[8];
#pragma unroll
        for (int j = 0; j < 8; ++j) rr[j] = __fmul_rn(xr[j], xr[j]);
#pragma unroll
        for (int i = 1; i < 8; ++i)
#pragma unroll
            for (int j = 0; j < 8; ++j)
                rr[j] = __fadd_rn(rr[j], __fmul_rn(xr[8*i + j], xr[8*i + j]));
        float t01 = __fadd_rn(rr[0], rr[1]);
        float t23 = __fadd_rn(rr[2], rr[3]);
        float t45 = __fadd_rn(rr[4], rr[5]);
        float t67 = __fadd_rn(rr[6], rr[7]);
        sqnp[r] = __fadd_rn(__fadd_rn(t01, t23), __fadd_rn(t45, t67));
    }

    // bf16 copy (identical bytes)
#pragma unroll
    for (int i = 0; i < 8; ++i) {
        uint4 u;
        u.x = pk2(xr[8*i+0], xr[8*i+1]);
        u.y = pk2(xr[8*i+2], xr[8*i+3]);
        u.z = pk2(xr[8*i+4], xr[8*i+5]);
        u.w = pk2(xr[8*i+6], xr[8*i+7]);
        xbu4[(size_t)r * 8 + i] = u;
    }

    __syncthreads();   // weights staged

    for (int o = 0; o < 64; o += 4) {
        float a4[4], b4[4];
#pragma unroll
        for (int oo = 0; oo < 4; ++oo) {
            const float* wmr  = &wm [(o + oo)*64];
            const float* w2mr = &w2m[(o + oo)*64];
            float a1 = 0.f, a2 = 0.f;
#pragma unroll
            for (int fi = 0; fi < 16; ++fi) {
                f32x4 wa = *(const f32x4*)&wmr [fi*4];
                f32x4 wb = *(const f32x4*)&w2mr[fi*4];
#pragma unroll
                for (int k = 0; k < 4; ++k) {
                    float xv = xr[fi*4 + k];
                    a1 = __builtin_fmaf(xv, wa[k], a1);
                    a2 = __builtin_fmaf(xv, wb[k], a2);
                }
            }
            a4[oo] = __fadd_rn(a1, bias[o + oo]);
            b4[oo] = a2;
        }
        *(float4*)&Aout[(size_t)r * 64 + o] = make_float4(a4[0], a4[1], a4[2], a4[3]);
        *(float4*)&Bvv [(size_t)r * 64 + o] = make_float4(b4[0], b4[1], b4[2], b4[3]);
    }
}

// Kernel 2 (R10 edit, unmeasured): same R0 structure/layout/numerics, two scheduling fixes:
//  1. prefetch loads issued at TOP of each ct (right after barrier) with A/B
//     register sets + 2x-unrolled loop -> the vmcnt(0) drain before s_barrier
//     comes ~1600 cyc after issue instead of ~0 (kills the per-ct load-drain).
//  2. __launch_bounds__(256,5): LDS 28160 caps us at 5 blocks/CU anyway, so
//     allow 102 VGPR (was 64-for-8-waves, over-provisioned) for better ILP.
// Spill check: WRITE_SIZE must stay ~24.6 MB.
__global__ __launch_bounds__(256, 5) void k_topk(const float4* __restrict__ x4,
    const uint4* __restrict__ xb, const float* __restrict__ sq, int* __restrict__ nbr)
{
    // phase1: bsh0 0..9216 | bsh1 9216..18432 | rsh 18432..27648 | sqc 27648..28160
    // phase2: cand 0..17408 | cand24 17408..20480
    __shared__ __align__(16) char smem[28160];
    unsigned short* bsh0 = (unsigned short*)smem;
    unsigned short* bsh1 = (unsigned short*)(smem + 9216);
    unsigned short* rsh  = (unsigned short*)(smem + 18432);
    float* sqc           = (float*)(smem + 27648);     // [2][64]
    unsigned int* cand   = (unsigned int*)smem;        // 64 rows x 68
    unsigned short* cand24 = (unsigned short*)(smem + 17408);

    int t = threadIdx.x;
    int lane = t & 63;
    int w = t >> 6;
    int ln = lane & 15, qd = lane >> 4;
    int batch = blockIdx.x >> 5;
    int strip = blockIdx.x & 31;
    int rbase = batch * NPERB;
    int r0g = rbase + strip * 64;

    unsigned int ks[16];
#pragma unroll
    for (int j = 0; j < 16; ++j) ks[j] = 0xFFFFFFFFu;

    // --- helpers (static indexing; no runtime-indexed reg arrays) ---
    auto issue_load = [&](int ct_, uint4& p0, uint4& p1, float& sp) {
        const uint4* src = xb + ((size_t)rbase + ct_*64) * 8;
        p0 = src[t]; p1 = src[t + 256];
        sp = (t < 64) ? sq[rbase + ct_*64 + t] : 0.f;
    };
    auto stage_write = [&](int ct_, uint4 p0, uint4 p1, float sp) {
        // writes tile (ct_+1) held in regs -> buf[(ct_+1)&1]
        unsigned short* bnext = ((ct_ + 1) & 1) ? bsh1 : bsh0;
        *(uint4*)&bnext[(t >> 3)*72 + (t & 7)*8] = p0;
        int l1 = t + 256;
        *(uint4*)&bnext[(l1 >> 3)*72 + (l1 & 7)*8] = p1;
        if (t < 64) sqc[((ct_ + 1) & 1)*64 + t] = sp;
    };

    // --- prologue ---
    {
        const uint4* src = xb + (size_t)r0g * 8;
#pragma unroll
        for (int i = 0; i < 2; ++i) {
            int l = t + i*256;
            uint4 v = src[l];
            *(uint4*)&rsh[(l >> 3)*72 + (l & 7)*8] = v;
        }
    }
    uint4 pA0, pA1, pB0, pB1; float sA, sB;
    issue_load(0, pA0, pA1, sA);
    __syncthreads();
    bf16x8 rf0 = *(const bf16x8*)&rsh[(w*16 + ln)*72 + qd*8];
    bf16x8 rf1 = *(const bf16x8*)&rsh[(w*16 + ln)*72 + 32 + qd*8];
    float sqr16 = sq[r0g + w*16 + ln] + 16.f;

    stage_write(-1, pA0, pA1, sA);      // tile0 -> bsh0, sqc[0]
    issue_load(1, pA0, pA1, sA);        // A := tile1
    __syncthreads();

    // --- main loop, 2x unrolled: invariant at even ct: buf[ct&1]=tile ct, A=tile ct+1 ---
    auto compute_tile = [&](int ct_, const unsigned short* bcur, const float* sqcur) {
#pragma unroll
        for (int ct2 = 0; ct2 < 4; ++ct2) {
            int pt = ct2*16 + ln;
            bf16x8 a0 = *(const bf16x8*)&bcur[pt*72 + qd*8];
            bf16x8 a1 = *(const bf16x8*)&bcur[pt*72 + 32 + qd*8];
            f32x4 acc = {0.f, 0.f, 0.f, 0.f};
            acc = __builtin_amdgcn_mfma_f32_16x16x32_bf16(a0, rf0, acc, 0, 0, 0);
            acc = __builtin_amdgcn_mfma_f32_16x16x32_bf16(a1, rf1, acc, 0, 0, 0);
            f32x4 sc4 = *(const f32x4*)&sqcur[ct2*16 + qd*4];
            int idxb = ct_*64 + ct2*16 + qd*4;
#pragma unroll
            for (int j = 0; j < 4; ++j) {
                float s = fmaf(-2.f, acc[j], sc4[j] + sqr16);   // > 0 always
                unsigned int u = (__float_as_uint(s) & 0xFFFFF800u) | (unsigned int)(idxb + j);
#pragma unroll
                for (int jj = 15; jj >= 1; --jj) ks[jj] = med3u(u, ks[jj-1], ks[jj]);
                ks[0] = min(ks[0], u);
            }
        }
    };

    for (int ct = 0; ct < 32; ct += 2) {
        // even half: compute tile ct (buf0), A holds tile ct+1, issue B := tile ct+2
        if (ct + 2 <= 31) issue_load(ct + 2, pB0, pB1, sB);
        compute_tile(ct, bsh0, sqc);
        stage_write(ct, pA0, pA1, sA);              // tile ct+1 -> bsh1 (ct<=30 always)
        __syncthreads();
        // odd half: compute tile ct+1 (buf1), B holds tile ct+2, issue A := tile ct+3
        if (ct + 3 <= 31) issue_load(ct + 3, pA0, pA1, sA);
        compute_tile(ct + 1, bsh1, sqc + 64);
        if (ct + 1 < 31) stage_write(ct + 1, pB0, pB1, sB);   // tile ct+2 -> bsh0
        __syncthreads();
    }

    // dump per-lane keys
    {
        int r = w*16 + ln;
#pragma unroll
        for (int j = 0; j < 16; ++j) cand[r*68 + qd*16 + j] = ks[j];
    }
    __syncthreads();

    // merge to bf16-top-24 per row
    if (t < 64) {
        unsigned int m24[NCAND];
#pragma unroll
        for (int j = 0; j < NCAND; ++j) m24[j] = 0xFFFFFFFFu;
        for (int i = 0; i < 64; ++i) {
            unsigned int u = cand[t*68 + i];
#pragma unroll
            for (int jj = NCAND-1; jj >= 1; --jj) m24[jj] = med3u(u, m24[jj-1], m24[jj]);
            m24[0] = min(m24[0], u);
        }
#pragma unroll
        for (int j = 0; j < NCAND; ++j) cand24[t*NCAND + j] = (unsigned short)(m24[j] & 0x7FFu);
    }
    __syncthreads();

    // np-exact rescore (R6-verified chain): 4 groups x 6 candidates per row
    {
        int r = t & 63, grp = t >> 6;
        float sqr = sq[r0g + r];
        float4 xrA[8];
#pragma unroll
        for (int i = 0; i < 8; ++i) xrA[i] = x4[(size_t)(r0g + r)*16 + i];
        float* kdf = (float*)cand;
#pragma unroll
        for (int m6 = 0; m6 < 6; ++m6) {
            int m = grp*6 + m6;
            int c = (int)cand24[r*NCAND + m];
            const float4* xb4 = &x4[(size_t)(rbase + c)*16];
            float dot = 0.f;
#pragma unroll
            for (int i = 0; i < 8; ++i) {
                float4 a = xrA[i]; float4 b = xb4[i];
                dot = fmaf(a.x, b.x, dot); dot = fmaf(a.y, b.y, dot);
                dot = fmaf(a.z, b.z, dot); dot = fmaf(a.w, b.w, dot);
            }
#pragma unroll
            for (int i = 8; i < 16; ++i) {
                float4 a = x4[(size_t)(r0g + r)*16 + i]; float4 b = xb4[i];
                dot = fmaf(a.x, b.x, dot); dot = fmaf(a.y, b.y, dot);
                dot = fmaf(a.z, b.z, dot); dot = fmaf(a.w, b.w, dot);
            }
            float kd = __fsub_rn(__fadd_rn(sqr, sq[rbase + c]), __fmul_rn(2.0f, dot));
            kdf[r*68 + m] = kd;
            cand[r*68 + 32 + m] = (unsigned int)c;
        }
    }
    __syncthreads();

    // exact top-16 with (key, idx) ordering
    if (t < 64) {
        float* kdf = (float*)cand;
        float dk[KNN]; int di[KNN];
#pragma unroll
        for (int j = 0; j < KNN; ++j) { dk[j] = FLT_MAX; di[j] = 0x7fffffff; }
        for (int m = 0; m < NCAND; ++m) {
            float kd = kdf[t*68 + m];
            int c = (int)cand[t*68 + 32 + m];
            bool better = (kd < dk[KNN-1]) || (kd == dk[KNN-1] && c < di[KNN-1]);
            if (better) {
#pragma unroll
                for (int j = KNN-1; j >= 1; --j) {
                    bool sh = (dk[j-1] > kd) || (dk[j-1] == kd && di[j-1] > c);
                    bool pl = (!sh) && ((dk[j] > kd) || (dk[j] == kd && di[j] > c));
                    float nk = sh ? dk[j-1] : (pl ? kd : dk[j]);
                    int ni = sh ? di[j-1] : (pl ? c : di[j]);
                    dk[j] = nk; di[j] = ni;
                }
                if ((dk[0] > kd) || (dk[0] == kd && di[0] > c)) { dk[0] = kd; di[0] = c; }
            }
        }
#pragma unroll
        for (int k = 0; k < KNN; ++k) nbr[(size_t)(r0g + t)*16 + k] = di[k];
    }
}

// Kernel 3: out[n,o] = relu(out[n,o] + max_k Bv[nbr_k, o])   (out holds A from k1)
__global__ __launch_bounds__(256) void k_combine(const float* __restrict__ Bvv,
    const int* __restrict__ nbr, float* __restrict__ out)
{
    int t = threadIdx.x;
    int row = blockIdx.x*4 + (t >> 6);
    int o = t & 63;
    int rb = (row >> 11) << 11;
    float m = -FLT_MAX;
#pragma unroll
    for (int k = 0; k < 16; ++k) {
        int c = nbr[(size_t)row*16 + k];
        m = fmaxf(m, Bvv[(size_t)(rb + c)*64 + o]);
    }
    out[(size_t)row*64 + o] = fmaxf(out[(size_t)row*64 + o] + m, 0.f);
}

extern "C" void kernel_launch(void* const* d_in, const int* in_sizes, int n_in,
                              void* d_out, int out_size, void* d_ws, size_t ws_size,
                              hipStream_t stream) {
    const float* x    = (const float*)d_in[0];
    // d_in[1] = batch (contiguous per batch; unused)
    const float* w    = (const float*)d_in[2];
    const float* bias = (const float*)d_in[3];
    float* out = (float*)d_out;

    float* Bvv  = (float*)d_ws;                       // 32 MB
    float* sqnp = Bvv + (size_t)NTOT * 64;            // 0.5 MB
    int*   nbr  = (int*)(sqnp + NTOT);                // 8 MB
    unsigned int* xbu = (unsigned int*)(nbr + (size_t)NTOT * 16);   // 16 MB bf16 x

    k_transform<<<NTOT/256, 256, 0, stream>>>((const float4*)x, w, bias, out, Bvv, sqnp, (uint4*)xbu);
    k_topk<<<2048, 256, 0, stream>>>((const float4*)x, (const uint4*)xbu, sqnp, nbr);
    k_combine<<<NTOT/4, 256, 0, stream>>>(Bvv, nbr, out);
}